// Round 6
// baseline (258.934 us; speedup 1.0000x reference)
//
#include <hip/hip_runtime.h>

#define N_NODES   100000
#define N_EDGES   1200000
#define D         64
#define N_GRAPHS  128
#define N_CLASSES 3

#define TILE      64                               // nodes per tile (layer + bucket)
#define NTILES    ((N_NODES + TILE - 1) / TILE)    // 1563
#define TCAP      1024                             // edges per tile bucket (mean 768, +9.2 sigma)
#define ASTRIDE   72                               // bf16 agg row stride (shorts): 144 B -> conflict-free b128

#define EPB       4096                             // edges per binA block
#define NEB       ((N_EDGES + EPB - 1) / EPB)      // 293
#define GRID_PB   1024                             // prep+binA fused grid

typedef unsigned int  uint;
typedef unsigned short ushort;
typedef __attribute__((ext_vector_type(8))) short bf16x8;   // 8 bf16 = 4 VGPRs (MFMA A/B frag)
typedef __attribute__((ext_vector_type(4))) float f32x4;    // MFMA C/D frag

// ------------------------------------------------------------- bf16 helpers
__device__ __forceinline__ ushort bf16_rne(float f) {
    uint u = __float_as_uint(f);
    u += 0x7FFFu + ((u >> 16) & 1u);      // round to nearest even
    return (ushort)(u >> 16);
}
__device__ __forceinline__ float bf16f(ushort h) {
    return __uint_as_float((uint)h << 16);
}
__device__ __forceinline__ void acc8(float* a, uint4 v) {
    a[0] += __uint_as_float(v.x << 16);
    a[1] += __uint_as_float(v.x & 0xFFFF0000u);
    a[2] += __uint_as_float(v.y << 16);
    a[3] += __uint_as_float(v.y & 0xFFFF0000u);
    a[4] += __uint_as_float(v.z << 16);
    a[5] += __uint_as_float(v.z & 0xFFFF0000u);
    a[6] += __uint_as_float(v.w << 16);
    a[7] += __uint_as_float(v.w & 0xFFFF0000u);
}

// gather over one adjacency segment, indices from LDS pointer cp.
// Wide ping-pong pipeline: 8-row batches, batch k+1's loads issued BEFORE
// accumulating batch k -> up to 16 rows in flight, never draining to zero
// inside a segment. Live regs ~ 2x8xuint4 (64) + 8 acc + addressing ~= 80,
// inside the ~84-VGPR cap of launch_bounds(256,6). Round-5's 4-wide variant
// was compressed to 32 VGPR by the allocator (pipeline defeated); the wide
// form gives it no cheap serialization. WRITE_SIZE is the spill tripwire.
__device__ __forceinline__ void gather_idx(
        float* acc, const int* cp, int len,
        const ushort* __restrict__ hin, int fq8) {
    int j = 0;
    if (len >= 8) {
        int t0 = cp[0], t1 = cp[1], t2 = cp[2], t3 = cp[3];
        int t4 = cp[4], t5 = cp[5], t6 = cp[6], t7 = cp[7];
        uint4 a0 = *(const uint4*)(hin + (size_t)t0 * D + fq8);
        uint4 a1 = *(const uint4*)(hin + (size_t)t1 * D + fq8);
        uint4 a2 = *(const uint4*)(hin + (size_t)t2 * D + fq8);
        uint4 a3 = *(const uint4*)(hin + (size_t)t3 * D + fq8);
        uint4 a4 = *(const uint4*)(hin + (size_t)t4 * D + fq8);
        uint4 a5 = *(const uint4*)(hin + (size_t)t5 * D + fq8);
        uint4 a6 = *(const uint4*)(hin + (size_t)t6 * D + fq8);
        uint4 a7 = *(const uint4*)(hin + (size_t)t7 * D + fq8);
        for (; j + 16 <= len; j += 8) {
            int s0 = cp[j + 8],  s1 = cp[j + 9],  s2 = cp[j + 10], s3 = cp[j + 11];
            int s4 = cp[j + 12], s5 = cp[j + 13], s6 = cp[j + 14], s7 = cp[j + 15];
            uint4 b0 = *(const uint4*)(hin + (size_t)s0 * D + fq8);
            uint4 b1 = *(const uint4*)(hin + (size_t)s1 * D + fq8);
            uint4 b2 = *(const uint4*)(hin + (size_t)s2 * D + fq8);
            uint4 b3 = *(const uint4*)(hin + (size_t)s3 * D + fq8);
            uint4 b4 = *(const uint4*)(hin + (size_t)s4 * D + fq8);
            uint4 b5 = *(const uint4*)(hin + (size_t)s5 * D + fq8);
            uint4 b6 = *(const uint4*)(hin + (size_t)s6 * D + fq8);
            uint4 b7 = *(const uint4*)(hin + (size_t)s7 * D + fq8);
            acc8(acc, a0); acc8(acc, a1); acc8(acc, a2); acc8(acc, a3);
            acc8(acc, a4); acc8(acc, a5); acc8(acc, a6); acc8(acc, a7);
            a0 = b0; a1 = b1; a2 = b2; a3 = b3;
            a4 = b4; a5 = b5; a6 = b6; a7 = b7;
        }
        acc8(acc, a0); acc8(acc, a1); acc8(acc, a2); acc8(acc, a3);
        acc8(acc, a4); acc8(acc, a5); acc8(acc, a6); acc8(acc, a7);
        j += 8;
    }
    for (; j + 4 <= len; j += 4) {
        int s0 = cp[j + 0], s1 = cp[j + 1], s2 = cp[j + 2], s3 = cp[j + 3];
        uint4 v0 = *(const uint4*)(hin + (size_t)s0 * D + fq8);
        uint4 v1 = *(const uint4*)(hin + (size_t)s1 * D + fq8);
        uint4 v2 = *(const uint4*)(hin + (size_t)s2 * D + fq8);
        uint4 v3 = *(const uint4*)(hin + (size_t)s3 * D + fq8);
        acc8(acc, v0); acc8(acc, v1); acc8(acc, v2); acc8(acc, v3);
    }
    for (; j < len; ++j) {
        uint4 v = *(const uint4*)(hin + (size_t)cp[j] * D + fq8);
        acc8(acc, v);
    }
}

// pack 8 f32 accumulators -> 8 bf16 -> one b128 LDS write (row ln, feats fq8..fq8+7)
__device__ __forceinline__ void store_agg_bf16(ushort* aggB, int ln, int fq8, const float* acc) {
    uint4 o;
    o.x = (uint)bf16_rne(acc[0]) | ((uint)bf16_rne(acc[1]) << 16);
    o.y = (uint)bf16_rne(acc[2]) | ((uint)bf16_rne(acc[3]) << 16);
    o.z = (uint)bf16_rne(acc[4]) | ((uint)bf16_rne(acc[5]) << 16);
    o.w = (uint)bf16_rne(acc[6]) | ((uint)bf16_rne(acc[7]) << 16);
    *(uint4*)&aggB[ln * ASTRIDE + fq8] = o;
}

// round pairing: r=0 -> rank g (low degrees), r=1 -> rank 63-g (high degrees).
// Each wave gets one low slice + one high slice: total gather work ~equal
// across the 4 waves (old r*32+g pairing gave wave 3 both median AND max tail).
__device__ __forceinline__ int pair_rank(int r, int g) {
    return r == 0 ? g : 63 - g;
}

// --------------------- MFMA GEMM: OUT[64 nodes][64 feat] = [aggB | x] @ (Whi+Wlo)
// Per wave w: N-cols [16w,16w+16), all 64 rows; K = 128 (64 agg + 64 x), hi/lo split.
// A frag: row = lane&15, k = (lane>>4)*8 + j (agg from LDS, x direct from global).
// B frags prepacked in Bp[kt(8)][w(4)][lane(64)][8] bf16 (kt = 2*st + {hi,lo}).
__device__ __forceinline__ void mfma_gemm(
        const ushort* __restrict__ hin,
        const ushort* aggB,
        const ushort* __restrict__ Bp,
        int node0, int tid, f32x4* acc) {
    const int lane = tid & 63;
    const int w    = tid >> 6;
    const int r16  = lane & 15;
    const int khi  = lane >> 4;
#pragma unroll
    for (int mt = 0; mt < 4; ++mt) acc[mt] = (f32x4){0.f, 0.f, 0.f, 0.f};
    const ushort* bp = Bp + (w * 64 + lane) * 8;
#pragma unroll
    for (int st = 0; st < 4; ++st) {
        bf16x8 bhi = *(const bf16x8*)(bp + (2 * st    ) * 2048);
        bf16x8 blo = *(const bf16x8*)(bp + (2 * st + 1) * 2048);
        if (st < 2) {                   // agg half: A frags from LDS (conflict-free b128)
#pragma unroll
            for (int mt = 0; mt < 4; ++mt) {
                bf16x8 a = *(const bf16x8*)(aggB + (16 * mt + r16) * ASTRIDE + st * 32 + khi * 8);
                acc[mt] = __builtin_amdgcn_mfma_f32_16x16x32_bf16(a, bhi, acc[mt], 0, 0, 0);
                acc[mt] = __builtin_amdgcn_mfma_f32_16x16x32_bf16(a, blo, acc[mt], 0, 0, 0);
            }
        } else {                        // x half: A frags straight from global bf16 rows
#pragma unroll
            for (int mt = 0; mt < 4; ++mt) {
                bf16x8 a = *(const bf16x8*)(hin + (size_t)(node0 + 16 * mt + r16) * D
                                                + (st - 2) * 32 + khi * 8);
                acc[mt] = __builtin_amdgcn_mfma_f32_16x16x32_bf16(a, bhi, acc[mt], 0, 0, 0);
                acc[mt] = __builtin_amdgcn_mfma_f32_16x16x32_bf16(a, blo, acc[mt], 0, 0, 0);
            }
        }
    }
}

// ---------- fused prep + binA (64-node buckets = layer tiles) + weight-frag packing
__global__ __launch_bounds__(256) void prep_binA_kernel(
        const float* __restrict__ x, ushort* __restrict__ Xb,
        const int* __restrict__ src, const int* __restrict__ dst,
        int* __restrict__ gcur, int* __restrict__ cbuf,
        const float* __restrict__ Wr1, const float* __restrict__ Ws1,
        const float* __restrict__ Wr2, const float* __restrict__ Ws2,
        const float* __restrict__ Wr3, const float* __restrict__ Ws3,
        ushort* __restrict__ Bp) {
    __shared__ int hist[NTILES];   // 6.25 KB
    __shared__ int pos[NTILES];    // 6.25 KB
    const int tid = threadIdx.x;
    const int bid = blockIdx.x;

    if (bid < NEB) {
        const int e0 = bid * EPB;
        int e1 = e0 + EPB; if (e1 > N_EDGES) e1 = N_EDGES;   // tail count 3968, %4==0
        for (int i = tid; i < NTILES; i += 256) hist[i] = 0;
        __syncthreads();
        for (int e = e0 + tid * 4; e < e1; e += 1024) {
            int4 d4 = *(const int4*)(dst + e);
            atomicAdd(&hist[d4.x >> 6], 1);
            atomicAdd(&hist[d4.y >> 6], 1);
            atomicAdd(&hist[d4.z >> 6], 1);
            atomicAdd(&hist[d4.w >> 6], 1);
        }
        __syncthreads();
        for (int b = tid; b < NTILES; b += 256)
            pos[b] = hist[b] ? atomicAdd(&gcur[b], hist[b]) : 0;
        __syncthreads();
        for (int e = e0 + tid * 4; e < e1; e += 1024) {
            int4 d4 = *(const int4*)(dst + e);
            int4 s4 = *(const int4*)(src + e);
#pragma unroll
            for (int k = 0; k < 4; ++k) {
                int d = (k == 0) ? d4.x : (k == 1) ? d4.y : (k == 2) ? d4.z : d4.w;
                int s = (k == 0) ? s4.x : (k == 1) ? s4.y : (k == 2) ? s4.z : s4.w;
                int b = d >> 6;
                int r = atomicAdd(&pos[b], 1);
                if (r < TCAP) cbuf[b * TCAP + r] = s | ((d & 63) << 17);
            }
        }
    } else {
        const int cb  = bid - NEB;
        const int NCB = GRID_PB - NEB;       // 731 convert blocks
        const int nodeF4 = N_NODES * D / 4;
        for (int i = cb * 256 + tid; i < nodeF4; i += NCB * 256) {
            float4 v = ((const float4*)x)[i];
            ushort4 o;
            o.x = bf16_rne(v.x); o.y = bf16_rne(v.y);
            o.z = bf16_rne(v.z); o.w = bf16_rne(v.w);
            ((ushort4*)Xb)[i] = o;
        }
        // ---- pack MFMA B-fragments: 3 layers x 8 kt x 4 waves x 64 lanes (one uint4 each)
        for (int it = cb * 256 + tid; it < 3 * 8 * 4 * 64; it += NCB * 256) {
            int l  = it & 63;
            int w  = (it >> 6) & 3;
            int kt = (it >> 8) & 7;
            int ly = it >> 11;
            int st = kt >> 1;                       // 0,1 = agg(Wr) | 2,3 = x(Ws)
            int col = w * 16 + (l & 15);
            int kb  = (st & 1) * 32 + (l >> 4) * 8;
            const float* W = (st < 2) ? (ly == 0 ? Wr1 : ly == 1 ? Wr2 : Wr3)
                                      : (ly == 0 ? Ws1 : ly == 1 ? Ws2 : Ws3);
            ushort o[8];
#pragma unroll
            for (int j = 0; j < 8; ++j) {
                float v = W[(kb + j) * D + col];
                ushort h = bf16_rne(v);
                if (kt & 1) {                       // lo residual: W - bf16(W)
                    float r = v - bf16f(h);
                    h = bf16_rne(r);
                }
                o[j] = h;
            }
            uint4 u;
            u.x = (uint)o[0] | ((uint)o[1] << 16);
            u.y = (uint)o[2] | ((uint)o[3] << 16);
            u.z = (uint)o[4] | ((uint)o[5] << 16);
            u.w = (uint)o[6] | ((uint)o[7] << 16);
            *(uint4*)(Bp + (size_t)ly * 16384 + ((kt * 4 + w) * 64 + l) * 8) = u;
        }
    }
}

// ---------- layer 1 fused with binB: sort tile's edges in LDS, emit dense
// CSR (csr + rptr2 for layers 2/3), degree-balanced gather, MFMA GEMM.
// launch_bounds(256,6): no-spill envelope. (256,8) caps at 32 VGPR ->
// scratch spill (+50 MB HBM round-trip, measured round 3). Do not raise.
__global__ __launch_bounds__(256, 6) void layer1_fused_kernel(
        const ushort* __restrict__ hin,
        const int* __restrict__ gcur,
        const int* __restrict__ cbuf,
        int* __restrict__ csr,
        int2* __restrict__ rptr2,
        const ushort* __restrict__ Bp,
        const float* __restrict__ br,
        ushort* __restrict__ hout) {
    __shared__ int    ebuf[TCAP];             // 4 KB
    __shared__ int    sortedS[TCAP];          // 4 KB
    __shared__ ushort aggB[TILE * ASTRIDE];   // 9.2 KB bf16 agg tile
    __shared__ int    ldeg[TILE];
    __shared__ int    lbeg[TILE];
    __shared__ int    lcur[TILE];
    __shared__ unsigned char permS[TILE];     // degree-sorted node order

    const int tid   = threadIdx.x;
    const int tile  = blockIdx.x;
    const int base  = tile * TCAP;
    const int node0 = tile * TILE;

    int E = gcur[tile]; if (E > TCAP) E = TCAP;
    if (tid < TILE) ldeg[tid] = 0;
    // one int4 per thread stages the whole TCAP bucket (stale tail never indexed)
    *(int4*)&ebuf[tid * 4] = *(const int4*)&cbuf[base + tid * 4];
    __syncthreads();

    for (int i = tid; i < E; i += 256)
        atomicAdd(&ldeg[(ebuf[i] >> 17) & 63], 1);
    __syncthreads();

    if (tid < TILE) {                       // wave-0: exclusive scan + degree rank
        int v = ldeg[tid];
        int s = v;
        for (int off = 1; off < 64; off <<= 1) {
            int u = __shfl_up(s, off, 64);
            if (tid >= off) s += u;
        }
        int beg = s - v;
        lbeg[tid] = beg;
        lcur[tid] = beg;
        int n = node0 + tid;
        if (n < N_NODES) rptr2[n] = make_int2(base + beg, base + beg + v);
        int rnk = 0;
        for (int j = 0; j < TILE; ++j) {
            int dj = ldeg[j];
            rnk += (dj < v) || (dj == v && j < tid);
        }
        permS[rnk] = (unsigned char)tid;
    }
    __syncthreads();

    for (int i = tid; i < E; i += 256) {
        int p  = ebuf[i];
        int ld = (p >> 17) & 63;
        int s  = p & 0x1FFFF;
        int q  = atomicAdd(&lcur[ld], 1);
        sortedS[q]    = s;
        csr[base + q] = s;                  // dense, block-owned region
    }
    __syncthreads();

    // ---- gather: degree-sorted slots, low+high round pairing per wave
    const int fq8 = (tid & 7) * 8;
    const int grp = tid >> 3;
    for (int r = 0; r < 2; ++r) {
        int ln = permS[pair_rank(r, grp)];
        float acc[8] = {0.f, 0.f, 0.f, 0.f, 0.f, 0.f, 0.f, 0.f};
        if (ldeg[ln] > 0)
            gather_idx(acc, (const int*)&sortedS[lbeg[ln]], ldeg[ln], hin, fq8);
        store_agg_bf16(aggB, ln, fq8, acc);
    }
    __syncthreads();

    f32x4 acc[4];
    mfma_gemm(hin, aggB, Bp, node0, tid, acc);

    const int lane = tid & 63;
    const int col  = (tid >> 6) * 16 + (lane & 15);
    const int khi  = lane >> 4;
    const float bias = br[col];
#pragma unroll
    for (int mt = 0; mt < 4; ++mt) {
#pragma unroll
        for (int i = 0; i < 4; ++i) {
            int n = node0 + 16 * mt + khi * 4 + i;
            if (n < N_NODES)
                hout[(size_t)n * D + col] = bf16_rne(fmaxf(acc[mt][i] + bias, 0.f));
        }
    }
}

// --------------------------- layers 2/3: LDS-staged CSR, degree-balanced gather
// launch_bounds(256,6): same no-spill envelope as layer1.
template<int DO_POOL>
__global__ __launch_bounds__(256, 6) void fused_layer_kernel(
        const ushort* __restrict__ hin,
        const int2* __restrict__ rptr2,
        const int* __restrict__ csr,
        const ushort* __restrict__ Bp,
        const float* __restrict__ br,
        ushort* __restrict__ hout,
        const int* __restrict__ batch,
        float* __restrict__ g) {
    __shared__ int    csrS[TCAP];             // 4 KB: whole tile CSR segment
    __shared__ ushort aggB[TILE * ASTRIDE];   // 9.2 KB
    __shared__ int    bS[TILE];
    __shared__ int    begS[TILE];
    __shared__ int    degS[TILE];
    __shared__ unsigned char permS[TILE];

    const int tid   = threadIdx.x;
    const int node0 = blockIdx.x * TILE;
    const int base  = blockIdx.x * TCAP;

    // stage CSR segment: one coalesced int4 per thread (stale tail never indexed)
    *(int4*)&csrS[tid * 4] = *(const int4*)&csr[base + tid * 4];

    if (tid < TILE) {
        int n = node0 + tid;
        if (DO_POOL) bS[tid] = (n < N_NODES) ? batch[n] : -1;
        int2 be = (n < N_NODES) ? rptr2[n] : make_int2(0, 0);
        begS[tid] = be.x - base;             // LDS-relative
        degS[tid] = be.y - be.x;
    }
    __syncthreads();
    if (tid < TILE) {
        int d = degS[tid];
        int rnk = 0;
        for (int j = 0; j < TILE; ++j) {
            int dj = degS[j];
            rnk += (dj < d) || (dj == d && j < tid);
        }
        permS[rnk] = (unsigned char)tid;
    }
    __syncthreads();

    const int fq8 = (tid & 7) * 8;
    const int grp = tid >> 3;
    for (int r = 0; r < 2; ++r) {
        int ln = permS[pair_rank(r, grp)];
        float acc[8] = {0.f, 0.f, 0.f, 0.f, 0.f, 0.f, 0.f, 0.f};
        if (degS[ln] > 0)
            gather_idx(acc, &csrS[begS[ln]], degS[ln], hin, fq8);
        store_agg_bf16(aggB, ln, fq8, acc);
    }
    __syncthreads();

    f32x4 acc[4];
    mfma_gemm(hin, aggB, Bp, node0, tid, acc);

    const int lane = tid & 63;
    const int col  = (tid >> 6) * 16 + (lane & 15);
    const int khi  = lane >> 4;
    const float bias = br[col];

    if (!DO_POOL) {
#pragma unroll
        for (int mt = 0; mt < 4; ++mt) {
#pragma unroll
            for (int i = 0; i < 4; ++i) {
                int n = node0 + 16 * mt + khi * 4 + i;
                if (n < N_NODES)
                    hout[(size_t)n * D + col] = bf16_rne(fmaxf(acc[mt][i] + bias, 0.f));
            }
        }
    } else {
        __syncthreads();   // all waves done reading aggB as MFMA A-operand
#pragma unroll
        for (int mt = 0; mt < 4; ++mt) {
#pragma unroll
            for (int i = 0; i < 4; ++i) {
                float v = fmaxf(acc[mt][i] + bias, 0.f);
                aggB[(16 * mt + khi * 4 + i) * ASTRIDE + col] = bf16_rne(v);
            }
        }
        __syncthreads();
        int f    = tid & 63;
        int part = tid >> 6;
        int ln0  = part * 16;
        int cur  = bS[ln0];
        float acc2 = 0.f;
        for (int ln = ln0; ln < ln0 + 16; ++ln) {
            int b = bS[ln];
            if (b < 0) break;
            if (b != cur) {
                atomicAdd(&g[cur * D + f], acc2);
                acc2 = 0.f;
                cur = b;
            }
            acc2 += bf16f(aggB[ln * ASTRIDE + f]);
        }
        if (cur >= 0) atomicAdd(&g[cur * D + f], acc2);
    }
}

// ------------------------------------------------------------------- MLP head
__global__ __launch_bounds__(64) void head_kernel(
        const float* __restrict__ g,
        const float* __restrict__ Wfc1, const float* __restrict__ bfc1,
        const float* __restrict__ Wfc2, const float* __restrict__ bfc2,
        float* __restrict__ out) {
    __shared__ float hS[D];
    __shared__ float lS[N_CLASSES];
    int gr = blockIdx.x;
    int f  = threadIdx.x;

    float acc = bfc1[f];
#pragma unroll
    for (int k = 0; k < D; ++k) acc += g[gr * D + k] * Wfc1[k * D + f];
    hS[f] = fmaxf(acc, 0.f);
    __syncthreads();

    if (f < N_CLASSES) {
        float a = bfc2[f];
#pragma unroll
        for (int k = 0; k < D; ++k) a += hS[k] * Wfc2[k * N_CLASSES + f];
        lS[f] = a;
    }
    __syncthreads();

    if (f == 0) {
        float m = fmaxf(lS[0], fmaxf(lS[1], lS[2]));
        float s = expf(lS[0] - m) + expf(lS[1] - m) + expf(lS[2] - m);
        float lse = m + logf(s);
        out[gr * 3 + 0] = lS[0] - lse;
        out[gr * 3 + 1] = lS[1] - lse;
        out[gr * 3 + 2] = lS[2] - lse;
    }
}

// ---------------------------------------------------------------------- launch
extern "C" void kernel_launch(void* const* d_in, const int* in_sizes, int n_in,
                              void* d_out, int out_size, void* d_ws, size_t ws_size,
                              hipStream_t stream) {
    const float* x     = (const float*)d_in[0];
    const int*   edge  = (const int*)d_in[1];
    const int*   batch = (const int*)d_in[2];
    const float* Wr1 = (const float*)d_in[3];
    const float* br1 = (const float*)d_in[4];
    const float* Ws1 = (const float*)d_in[5];
    const float* Wr2 = (const float*)d_in[6];
    const float* br2 = (const float*)d_in[7];
    const float* Ws2 = (const float*)d_in[8];
    const float* Wr3 = (const float*)d_in[9];
    const float* br3 = (const float*)d_in[10];
    const float* Ws3 = (const float*)d_in[11];
    const float* Wfc1 = (const float*)d_in[12];
    const float* bfc1 = (const float*)d_in[13];
    const float* Wfc2 = (const float*)d_in[14];
    const float* bfc2 = (const float*)d_in[15];

    const int* src = edge;
    const int* dst = edge + N_EDGES;

    // workspace layout (16 B aligned), ~39.4 MB total
    ushort* Xb     = (ushort*)d_ws;                       // 6.4M bf16 (12.8 MB)
    ushort* Ab     = Xb + (size_t)N_NODES * D;            // 6.4M bf16 (12.8 MB)
    float*  g      = (float*)(Ab + (size_t)N_NODES * D);  // 8192 f
    int*   gcur    = (int*)(g + (size_t)N_GRAPHS * D);    // 1564 i (zeroed w/ g)
    int2*  rptr2   = (int2*)(gcur + 1564);                // 100,000 int2 (0.8 MB)
    int*   cbuf    = (int*)(rptr2 + N_NODES);             // 1563*1024 i (6.4 MB)
    int*   csr     = cbuf + (size_t)NTILES * TCAP;        // 1563*1024 i (6.4 MB)
    ushort* Bp     = (ushort*)(csr + (size_t)NTILES * TCAP); // 3 x 16384 bf16 (96 KB)

    dim3 blk256(256);
    dim3 grdT((int)NTILES);                               // 1563

    // ---- zero g + gcur via graph-capturable DMA memset
    hipMemsetAsync(g, 0, (size_t)(N_GRAPHS * D + 1564) * sizeof(float), stream);

    // ---- fused prep(x->bf16) + binA partition + B-fragment packing
    prep_binA_kernel<<<dim3(GRID_PB), blk256, 0, stream>>>(
        x, Xb, src, dst, gcur, cbuf, Wr1, Ws1, Wr2, Ws2, Wr3, Ws3, Bp);

    // ---- layer 1 (fused with per-tile edge sort; emits csr + rptr2)
    layer1_fused_kernel<<<grdT, blk256, 0, stream>>>(Xb, gcur, cbuf, csr, rptr2,
                                                     Bp, br1, Ab);

    // ---- layers 2,3 (dense CSR; layer 3 pools into g)
    fused_layer_kernel<0><<<grdT, blk256, 0, stream>>>(Ab, rptr2, csr, Bp + 16384, br2, Xb, batch, g);
    fused_layer_kernel<1><<<grdT, blk256, 0, stream>>>(Xb, rptr2, csr, Bp + 32768, br3, Ab, batch, g);

    // ---- head
    head_kernel<<<dim3(N_GRAPHS), dim3(64), 0, stream>>>(g, Wfc1, bfc1, Wfc2, bfc2, (float*)d_out);
}

// Round 7
// 222.599 us; speedup vs baseline: 1.1632x; 1.1632x over previous
//
#include <hip/hip_runtime.h>

#define N_NODES   100000
#define N_EDGES   1200000
#define D         64
#define N_GRAPHS  128
#define N_CLASSES 3

#define TILE      64                               // nodes per tile (layer + bucket)
#define NTILES    ((N_NODES + TILE - 1) / TILE)    // 1563
#define TCAP      1024                             // edges per tile bucket (mean 768, +9.2 sigma)
#define ASTRIDE   72                               // bf16 agg row stride (shorts): 144 B -> conflict-free b128

#define EPB       4096                             // edges per binA block
#define NEB       ((N_EDGES + EPB - 1) / EPB)      // 293
#define GRID_PB   1024                             // prep+binA fused grid

typedef unsigned int  uint;
typedef unsigned short ushort;
typedef __attribute__((ext_vector_type(8))) short bf16x8;   // 8 bf16 = 4 VGPRs (MFMA A/B frag)
typedef __attribute__((ext_vector_type(4))) float f32x4;    // MFMA C/D frag

// ------------------------------------------------------------- bf16 helpers
__device__ __forceinline__ ushort bf16_rne(float f) {
    uint u = __float_as_uint(f);
    u += 0x7FFFu + ((u >> 16) & 1u);      // round to nearest even
    return (ushort)(u >> 16);
}
__device__ __forceinline__ float bf16f(ushort h) {
    return __uint_as_float((uint)h << 16);
}
__device__ __forceinline__ void acc8(float* a, uint4 v) {
    a[0] += __uint_as_float(v.x << 16);
    a[1] += __uint_as_float(v.x & 0xFFFF0000u);
    a[2] += __uint_as_float(v.y << 16);
    a[3] += __uint_as_float(v.y & 0xFFFF0000u);
    a[4] += __uint_as_float(v.z << 16);
    a[5] += __uint_as_float(v.z & 0xFFFF0000u);
    a[6] += __uint_as_float(v.w << 16);
    a[7] += __uint_as_float(v.w & 0xFFFF0000u);
}

// gather over one adjacency segment, indices from LDS pointer cp.
// 4-wide ping-pong (round-5 proven best, 225.3 us): batch k+1's 4 row-loads
// issued BEFORE accumulating batch k. DO NOT widen to 8x2: the allocator
// spills the pipeline to scratch (round 6: +15 MB HBM round-trip, +33 us).
// DO NOT raise launch_bounds past (256,6): round-3 spill disaster.
__device__ __forceinline__ void gather_idx(
        float* acc, const int* cp, int len,
        const ushort* __restrict__ hin, int fq8) {
    int j = 0;
    uint4 a0, a1, a2, a3;
    if (len >= 4) {
        int s0 = cp[0], s1 = cp[1], s2 = cp[2], s3 = cp[3];
        a0 = *(const uint4*)(hin + (size_t)s0 * D + fq8);
        a1 = *(const uint4*)(hin + (size_t)s1 * D + fq8);
        a2 = *(const uint4*)(hin + (size_t)s2 * D + fq8);
        a3 = *(const uint4*)(hin + (size_t)s3 * D + fq8);
    }
    for (; j + 8 <= len; j += 4) {
        int s0 = cp[j + 4], s1 = cp[j + 5], s2 = cp[j + 6], s3 = cp[j + 7];
        uint4 b0 = *(const uint4*)(hin + (size_t)s0 * D + fq8);
        uint4 b1 = *(const uint4*)(hin + (size_t)s1 * D + fq8);
        uint4 b2 = *(const uint4*)(hin + (size_t)s2 * D + fq8);
        uint4 b3 = *(const uint4*)(hin + (size_t)s3 * D + fq8);
        acc8(acc, a0); acc8(acc, a1); acc8(acc, a2); acc8(acc, a3);
        a0 = b0; a1 = b1; a2 = b2; a3 = b3;
    }
    if (j + 4 <= len) {                       // drain the preloaded batch
        acc8(acc, a0); acc8(acc, a1); acc8(acc, a2); acc8(acc, a3);
        j += 4;
    }
    for (; j < len; ++j) {
        uint4 v = *(const uint4*)(hin + (size_t)cp[j] * D + fq8);
        acc8(acc, v);
    }
}

// pack 8 f32 accumulators -> 8 bf16 -> one b128 LDS write (row ln, feats fq8..fq8+7)
__device__ __forceinline__ void store_agg_bf16(ushort* aggB, int ln, int fq8, const float* acc) {
    uint4 o;
    o.x = (uint)bf16_rne(acc[0]) | ((uint)bf16_rne(acc[1]) << 16);
    o.y = (uint)bf16_rne(acc[2]) | ((uint)bf16_rne(acc[3]) << 16);
    o.z = (uint)bf16_rne(acc[4]) | ((uint)bf16_rne(acc[5]) << 16);
    o.w = (uint)bf16_rne(acc[6]) | ((uint)bf16_rne(acc[7]) << 16);
    *(uint4*)&aggB[ln * ASTRIDE + fq8] = o;
}

// round pairing: r=0 -> rank g (low degrees), r=1 -> rank 63-g (high degrees).
// Each wave gets one low slice + one high slice: total gather work ~equal
// across the 4 waves. Register-neutral (round-6's regression was the spill,
// not this pairing).
__device__ __forceinline__ int pair_rank(int r, int g) {
    return r == 0 ? g : 63 - g;
}

// --------------------- MFMA GEMM: OUT[64 nodes][64 feat] = [aggB | x] @ (Whi+Wlo)
// Per wave w: N-cols [16w,16w+16), all 64 rows; K = 128 (64 agg + 64 x), hi/lo split.
// A frag: row = lane&15, k = (lane>>4)*8 + j (agg from LDS, x direct from global).
// B frags prepacked in Bp[kt(8)][w(4)][lane(64)][8] bf16 (kt = 2*st + {hi,lo}).
__device__ __forceinline__ void mfma_gemm(
        const ushort* __restrict__ hin,
        const ushort* aggB,
        const ushort* __restrict__ Bp,
        int node0, int tid, f32x4* acc) {
    const int lane = tid & 63;
    const int w    = tid >> 6;
    const int r16  = lane & 15;
    const int khi  = lane >> 4;
#pragma unroll
    for (int mt = 0; mt < 4; ++mt) acc[mt] = (f32x4){0.f, 0.f, 0.f, 0.f};
    const ushort* bp = Bp + (w * 64 + lane) * 8;
#pragma unroll
    for (int st = 0; st < 4; ++st) {
        bf16x8 bhi = *(const bf16x8*)(bp + (2 * st    ) * 2048);
        bf16x8 blo = *(const bf16x8*)(bp + (2 * st + 1) * 2048);
        if (st < 2) {                   // agg half: A frags from LDS (conflict-free b128)
#pragma unroll
            for (int mt = 0; mt < 4; ++mt) {
                bf16x8 a = *(const bf16x8*)(aggB + (16 * mt + r16) * ASTRIDE + st * 32 + khi * 8);
                acc[mt] = __builtin_amdgcn_mfma_f32_16x16x32_bf16(a, bhi, acc[mt], 0, 0, 0);
                acc[mt] = __builtin_amdgcn_mfma_f32_16x16x32_bf16(a, blo, acc[mt], 0, 0, 0);
            }
        } else {                        // x half: A frags straight from global bf16 rows
#pragma unroll
            for (int mt = 0; mt < 4; ++mt) {
                bf16x8 a = *(const bf16x8*)(hin + (size_t)(node0 + 16 * mt + r16) * D
                                                + (st - 2) * 32 + khi * 8);
                acc[mt] = __builtin_amdgcn_mfma_f32_16x16x32_bf16(a, bhi, acc[mt], 0, 0, 0);
                acc[mt] = __builtin_amdgcn_mfma_f32_16x16x32_bf16(a, blo, acc[mt], 0, 0, 0);
            }
        }
    }
}

// ---------- fused prep + binA (64-node buckets = layer tiles) + weight-frag packing
__global__ __launch_bounds__(256) void prep_binA_kernel(
        const float* __restrict__ x, ushort* __restrict__ Xb,
        const int* __restrict__ src, const int* __restrict__ dst,
        int* __restrict__ gcur, int* __restrict__ cbuf,
        const float* __restrict__ Wr1, const float* __restrict__ Ws1,
        const float* __restrict__ Wr2, const float* __restrict__ Ws2,
        const float* __restrict__ Wr3, const float* __restrict__ Ws3,
        ushort* __restrict__ Bp) {
    __shared__ int hist[NTILES];   // 6.25 KB
    __shared__ int pos[NTILES];    // 6.25 KB
    const int tid = threadIdx.x;
    const int bid = blockIdx.x;

    if (bid < NEB) {
        const int e0 = bid * EPB;
        int e1 = e0 + EPB; if (e1 > N_EDGES) e1 = N_EDGES;   // tail count 3968, %4==0
        for (int i = tid; i < NTILES; i += 256) hist[i] = 0;
        __syncthreads();
        for (int e = e0 + tid * 4; e < e1; e += 1024) {
            int4 d4 = *(const int4*)(dst + e);
            atomicAdd(&hist[d4.x >> 6], 1);
            atomicAdd(&hist[d4.y >> 6], 1);
            atomicAdd(&hist[d4.z >> 6], 1);
            atomicAdd(&hist[d4.w >> 6], 1);
        }
        __syncthreads();
        for (int b = tid; b < NTILES; b += 256)
            pos[b] = hist[b] ? atomicAdd(&gcur[b], hist[b]) : 0;
        __syncthreads();
        for (int e = e0 + tid * 4; e < e1; e += 1024) {
            int4 d4 = *(const int4*)(dst + e);
            int4 s4 = *(const int4*)(src + e);
#pragma unroll
            for (int k = 0; k < 4; ++k) {
                int d = (k == 0) ? d4.x : (k == 1) ? d4.y : (k == 2) ? d4.z : d4.w;
                int s = (k == 0) ? s4.x : (k == 1) ? s4.y : (k == 2) ? s4.z : s4.w;
                int b = d >> 6;
                int r = atomicAdd(&pos[b], 1);
                if (r < TCAP) cbuf[b * TCAP + r] = s | ((d & 63) << 17);
            }
        }
    } else {
        const int cb  = bid - NEB;
        const int NCB = GRID_PB - NEB;       // 731 convert blocks
        const int nodeF4 = N_NODES * D / 4;
        for (int i = cb * 256 + tid; i < nodeF4; i += NCB * 256) {
            float4 v = ((const float4*)x)[i];
            ushort4 o;
            o.x = bf16_rne(v.x); o.y = bf16_rne(v.y);
            o.z = bf16_rne(v.z); o.w = bf16_rne(v.w);
            ((ushort4*)Xb)[i] = o;
        }
        // ---- pack MFMA B-fragments: 3 layers x 8 kt x 4 waves x 64 lanes (one uint4 each)
        for (int it = cb * 256 + tid; it < 3 * 8 * 4 * 64; it += NCB * 256) {
            int l  = it & 63;
            int w  = (it >> 6) & 3;
            int kt = (it >> 8) & 7;
            int ly = it >> 11;
            int st = kt >> 1;                       // 0,1 = agg(Wr) | 2,3 = x(Ws)
            int col = w * 16 + (l & 15);
            int kb  = (st & 1) * 32 + (l >> 4) * 8;
            const float* W = (st < 2) ? (ly == 0 ? Wr1 : ly == 1 ? Wr2 : Wr3)
                                      : (ly == 0 ? Ws1 : ly == 1 ? Ws2 : Ws3);
            ushort o[8];
#pragma unroll
            for (int j = 0; j < 8; ++j) {
                float v = W[(kb + j) * D + col];
                ushort h = bf16_rne(v);
                if (kt & 1) {                       // lo residual: W - bf16(W)
                    float r = v - bf16f(h);
                    h = bf16_rne(r);
                }
                o[j] = h;
            }
            uint4 u;
            u.x = (uint)o[0] | ((uint)o[1] << 16);
            u.y = (uint)o[2] | ((uint)o[3] << 16);
            u.z = (uint)o[4] | ((uint)o[5] << 16);
            u.w = (uint)o[6] | ((uint)o[7] << 16);
            *(uint4*)(Bp + (size_t)ly * 16384 + ((kt * 4 + w) * 64 + l) * 8) = u;
        }
    }
}

// ---------- layer 1 fused with binB: sort tile's edges in LDS, emit dense
// CSR (csr + rptr2 for layers 2/3), degree-balanced gather, MFMA GEMM.
// launch_bounds(256,6): no-spill envelope. (256,8) caps at 32 VGPR ->
// scratch spill (+50 MB HBM round-trip, measured round 3). Do not raise.
__global__ __launch_bounds__(256, 6) void layer1_fused_kernel(
        const ushort* __restrict__ hin,
        const int* __restrict__ gcur,
        const int* __restrict__ cbuf,
        int* __restrict__ csr,
        int2* __restrict__ rptr2,
        const ushort* __restrict__ Bp,
        const float* __restrict__ br,
        ushort* __restrict__ hout) {
    __shared__ int    ebuf[TCAP];             // 4 KB
    __shared__ int    sortedS[TCAP];          // 4 KB
    __shared__ ushort aggB[TILE * ASTRIDE];   // 9.2 KB bf16 agg tile
    __shared__ int    ldeg[TILE];
    __shared__ int    lbeg[TILE];
    __shared__ int    lcur[TILE];
    __shared__ unsigned char permS[TILE];     // degree-sorted node order

    const int tid   = threadIdx.x;
    const int tile  = blockIdx.x;
    const int base  = tile * TCAP;
    const int node0 = tile * TILE;

    int E = gcur[tile]; if (E > TCAP) E = TCAP;
    if (tid < TILE) ldeg[tid] = 0;
    // one int4 per thread stages the whole TCAP bucket (stale tail never indexed)
    *(int4*)&ebuf[tid * 4] = *(const int4*)&cbuf[base + tid * 4];
    __syncthreads();

    for (int i = tid; i < E; i += 256)
        atomicAdd(&ldeg[(ebuf[i] >> 17) & 63], 1);
    __syncthreads();

    if (tid < TILE) {                       // wave-0: exclusive scan + degree rank
        int v = ldeg[tid];
        int s = v;
        for (int off = 1; off < 64; off <<= 1) {
            int u = __shfl_up(s, off, 64);
            if (tid >= off) s += u;
        }
        int beg = s - v;
        lbeg[tid] = beg;
        lcur[tid] = beg;
        int n = node0 + tid;
        if (n < N_NODES) rptr2[n] = make_int2(base + beg, base + beg + v);
        int rnk = 0;
        for (int j = 0; j < TILE; ++j) {
            int dj = ldeg[j];
            rnk += (dj < v) || (dj == v && j < tid);
        }
        permS[rnk] = (unsigned char)tid;
    }
    __syncthreads();

    for (int i = tid; i < E; i += 256) {
        int p  = ebuf[i];
        int ld = (p >> 17) & 63;
        int s  = p & 0x1FFFF;
        int q  = atomicAdd(&lcur[ld], 1);
        sortedS[q]    = s;
        csr[base + q] = s;                  // dense, block-owned region
    }
    __syncthreads();

    // ---- gather: degree-sorted slots, low+high round pairing per wave
    const int fq8 = (tid & 7) * 8;
    const int grp = tid >> 3;
    for (int r = 0; r < 2; ++r) {
        int ln = permS[pair_rank(r, grp)];
        float acc[8] = {0.f, 0.f, 0.f, 0.f, 0.f, 0.f, 0.f, 0.f};
        if (ldeg[ln] > 0)
            gather_idx(acc, (const int*)&sortedS[lbeg[ln]], ldeg[ln], hin, fq8);
        store_agg_bf16(aggB, ln, fq8, acc);
    }
    __syncthreads();

    f32x4 acc[4];
    mfma_gemm(hin, aggB, Bp, node0, tid, acc);

    const int lane = tid & 63;
    const int col  = (tid >> 6) * 16 + (lane & 15);
    const int khi  = lane >> 4;
    const float bias = br[col];
#pragma unroll
    for (int mt = 0; mt < 4; ++mt) {
#pragma unroll
        for (int i = 0; i < 4; ++i) {
            int n = node0 + 16 * mt + khi * 4 + i;
            if (n < N_NODES)
                hout[(size_t)n * D + col] = bf16_rne(fmaxf(acc[mt][i] + bias, 0.f));
        }
    }
}

// --------------------------- layers 2/3: LDS-staged CSR, degree-balanced gather
// launch_bounds(256,6): same no-spill envelope as layer1.
template<int DO_POOL>
__global__ __launch_bounds__(256, 6) void fused_layer_kernel(
        const ushort* __restrict__ hin,
        const int2* __restrict__ rptr2,
        const int* __restrict__ csr,
        const ushort* __restrict__ Bp,
        const float* __restrict__ br,
        ushort* __restrict__ hout,
        const int* __restrict__ batch,
        float* __restrict__ g) {
    __shared__ int    csrS[TCAP];             // 4 KB: whole tile CSR segment
    __shared__ ushort aggB[TILE * ASTRIDE];   // 9.2 KB
    __shared__ int    bS[TILE];
    __shared__ int    begS[TILE];
    __shared__ int    degS[TILE];
    __shared__ unsigned char permS[TILE];

    const int tid   = threadIdx.x;
    const int node0 = blockIdx.x * TILE;
    const int base  = blockIdx.x * TCAP;

    // stage CSR segment: one coalesced int4 per thread (stale tail never indexed)
    *(int4*)&csrS[tid * 4] = *(const int4*)&csr[base + tid * 4];

    if (tid < TILE) {
        int n = node0 + tid;
        if (DO_POOL) bS[tid] = (n < N_NODES) ? batch[n] : -1;
        int2 be = (n < N_NODES) ? rptr2[n] : make_int2(0, 0);
        begS[tid] = be.x - base;             // LDS-relative
        degS[tid] = be.y - be.x;
    }
    __syncthreads();
    if (tid < TILE) {
        int d = degS[tid];
        int rnk = 0;
        for (int j = 0; j < TILE; ++j) {
            int dj = degS[j];
            rnk += (dj < d) || (dj == d && j < tid);
        }
        permS[rnk] = (unsigned char)tid;
    }
    __syncthreads();

    const int fq8 = (tid & 7) * 8;
    const int grp = tid >> 3;
    for (int r = 0; r < 2; ++r) {
        int ln = permS[pair_rank(r, grp)];
        float acc[8] = {0.f, 0.f, 0.f, 0.f, 0.f, 0.f, 0.f, 0.f};
        if (degS[ln] > 0)
            gather_idx(acc, &csrS[begS[ln]], degS[ln], hin, fq8);
        store_agg_bf16(aggB, ln, fq8, acc);
    }
    __syncthreads();

    f32x4 acc[4];
    mfma_gemm(hin, aggB, Bp, node0, tid, acc);

    const int lane = tid & 63;
    const int col  = (tid >> 6) * 16 + (lane & 15);
    const int khi  = lane >> 4;
    const float bias = br[col];

    if (!DO_POOL) {
#pragma unroll
        for (int mt = 0; mt < 4; ++mt) {
#pragma unroll
            for (int i = 0; i < 4; ++i) {
                int n = node0 + 16 * mt + khi * 4 + i;
                if (n < N_NODES)
                    hout[(size_t)n * D + col] = bf16_rne(fmaxf(acc[mt][i] + bias, 0.f));
            }
        }
    } else {
        __syncthreads();   // all waves done reading aggB as MFMA A-operand
#pragma unroll
        for (int mt = 0; mt < 4; ++mt) {
#pragma unroll
            for (int i = 0; i < 4; ++i) {
                float v = fmaxf(acc[mt][i] + bias, 0.f);
                aggB[(16 * mt + khi * 4 + i) * ASTRIDE + col] = bf16_rne(v);
            }
        }
        __syncthreads();
        int f    = tid & 63;
        int part = tid >> 6;
        int ln0  = part * 16;
        int cur  = bS[ln0];
        float acc2 = 0.f;
        for (int ln = ln0; ln < ln0 + 16; ++ln) {
            int b = bS[ln];
            if (b < 0) break;
            if (b != cur) {
                atomicAdd(&g[cur * D + f], acc2);
                acc2 = 0.f;
                cur = b;
            }
            acc2 += bf16f(aggB[ln * ASTRIDE + f]);
        }
        if (cur >= 0) atomicAdd(&g[cur * D + f], acc2);
    }
}

// ------------------------------------------------------------------- MLP head
__global__ __launch_bounds__(64) void head_kernel(
        const float* __restrict__ g,
        const float* __restrict__ Wfc1, const float* __restrict__ bfc1,
        const float* __restrict__ Wfc2, const float* __restrict__ bfc2,
        float* __restrict__ out) {
    __shared__ float hS[D];
    __shared__ float lS[N_CLASSES];
    int gr = blockIdx.x;
    int f  = threadIdx.x;

    float acc = bfc1[f];
#pragma unroll
    for (int k = 0; k < D; ++k) acc += g[gr * D + k] * Wfc1[k * D + f];
    hS[f] = fmaxf(acc, 0.f);
    __syncthreads();

    if (f < N_CLASSES) {
        float a = bfc2[f];
#pragma unroll
        for (int k = 0; k < D; ++k) a += hS[k] * Wfc2[k * N_CLASSES + f];
        lS[f] = a;
    }
    __syncthreads();

    if (f == 0) {
        float m = fmaxf(lS[0], fmaxf(lS[1], lS[2]));
        float s = expf(lS[0] - m) + expf(lS[1] - m) + expf(lS[2] - m);
        float lse = m + logf(s);
        out[gr * 3 + 0] = lS[0] - lse;
        out[gr * 3 + 1] = lS[1] - lse;
        out[gr * 3 + 2] = lS[2] - lse;
    }
}

// ---------------------------------------------------------------------- launch
extern "C" void kernel_launch(void* const* d_in, const int* in_sizes, int n_in,
                              void* d_out, int out_size, void* d_ws, size_t ws_size,
                              hipStream_t stream) {
    const float* x     = (const float*)d_in[0];
    const int*   edge  = (const int*)d_in[1];
    const int*   batch = (const int*)d_in[2];
    const float* Wr1 = (const float*)d_in[3];
    const float* br1 = (const float*)d_in[4];
    const float* Ws1 = (const float*)d_in[5];
    const float* Wr2 = (const float*)d_in[6];
    const float* br2 = (const float*)d_in[7];
    const float* Ws2 = (const float*)d_in[8];
    const float* Wr3 = (const float*)d_in[9];
    const float* br3 = (const float*)d_in[10];
    const float* Ws3 = (const float*)d_in[11];
    const float* Wfc1 = (const float*)d_in[12];
    const float* bfc1 = (const float*)d_in[13];
    const float* Wfc2 = (const float*)d_in[14];
    const float* bfc2 = (const float*)d_in[15];

    const int* src = edge;
    const int* dst = edge + N_EDGES;

    // workspace layout (16 B aligned), ~39.4 MB total
    ushort* Xb     = (ushort*)d_ws;                       // 6.4M bf16 (12.8 MB)
    ushort* Ab     = Xb + (size_t)N_NODES * D;            // 6.4M bf16 (12.8 MB)
    float*  g      = (float*)(Ab + (size_t)N_NODES * D);  // 8192 f
    int*   gcur    = (int*)(g + (size_t)N_GRAPHS * D);    // 1564 i (zeroed w/ g)
    int2*  rptr2   = (int2*)(gcur + 1564);                // 100,000 int2 (0.8 MB)
    int*   cbuf    = (int*)(rptr2 + N_NODES);             // 1563*1024 i (6.4 MB)
    int*   csr     = cbuf + (size_t)NTILES * TCAP;        // 1563*1024 i (6.4 MB)
    ushort* Bp     = (ushort*)(csr + (size_t)NTILES * TCAP); // 3 x 16384 bf16 (96 KB)

    dim3 blk256(256);
    dim3 grdT((int)NTILES);                               // 1563

    // ---- zero g + gcur via graph-capturable DMA memset
    hipMemsetAsync(g, 0, (size_t)(N_GRAPHS * D + 1564) * sizeof(float), stream);

    // ---- fused prep(x->bf16) + binA partition + B-fragment packing
    prep_binA_kernel<<<dim3(GRID_PB), blk256, 0, stream>>>(
        x, Xb, src, dst, gcur, cbuf, Wr1, Ws1, Wr2, Ws2, Wr3, Ws3, Bp);

    // ---- layer 1 (fused with per-tile edge sort; emits csr + rptr2)
    layer1_fused_kernel<<<grdT, blk256, 0, stream>>>(Xb, gcur, cbuf, csr, rptr2,
                                                     Bp, br1, Ab);

    // ---- layers 2,3 (dense CSR; layer 3 pools into g)
    fused_layer_kernel<0><<<grdT, blk256, 0, stream>>>(Ab, rptr2, csr, Bp + 16384, br2, Xb, batch, g);
    fused_layer_kernel<1><<<grdT, blk256, 0, stream>>>(Xb, rptr2, csr, Bp + 32768, br3, Ab, batch, g);

    // ---- head
    head_kernel<<<dim3(N_GRAPHS), dim3(64), 0, stream>>>(g, Wfc1, bfc1, Wfc2, bfc2, (float*)d_out);
}